// Round 11
// baseline (246.450 us; speedup 1.0000x reference)
//
#include <hip/hip_runtime.h>

#define N_NODES 50000
#define F_IN 128
#define F_OUT 32
#define E_L 800000
#define NEG_SLOPE 0.2f
#define LN 100000                 // 2 * N_NODES
#define NE 1600000                // 2 * E_L random edges
#define BSH 6                     // 64 nodes per bucket
#define BNODES 64
#define NB 782                    // ceil(50000/64)
#define CAP 2368                  // bucket cap: mean 2048 + ~10 sigma
#define HCAP 1280                 // half-bucket cap: mean 1024 + 8 sigma
#define PBLOCKS 256
#define PCHUNK 6250               // PBLOCKS * PCHUNK == NE; 128*6250 == E_L
#define CEDGE 13                  // ceil(PCHUNK / 512)

// ---------------------------------------------------------------------------
// K1: bucket partition (unchanged from r10 — measured-best structure).
// trg entry packed (rr:7 | u:17), rr=(l<<6)|(trg&63), u=src+l*N; src side
// 1-byte (l<<6)|(src&63). Block-level LDS hist reserves contiguous global
// ranges; phase A caches the LDS atomic's return -> phase C has zero atomics.
// NO global atomics (r8: 3.2M device-scope atomics = ~102MB fabric RMW).
// ---------------------------------------------------------------------------
__global__ __launch_bounds__(512) void partition_kernel(
    const int* __restrict__ e0, const int* __restrict__ e1,
    int* __restrict__ cur_t, int* __restrict__ cur_s,
    int* __restrict__ trgbuf, unsigned char* __restrict__ srcbuf) {
    __shared__ int hist_t[NB], hist_s[NB], res_t[NB], res_s[NB];
    const int t = threadIdx.x, b = blockIdx.x;
    const int l = (b >= PBLOCKS / 2) ? 1 : 0;
    const int* __restrict__ ei = l ? e1 : e0;
    const int ebase = b * PCHUNK - l * E_L;     // in-layer edge base
    for (int i = t; i < NB; i += 512) { hist_t[i] = 0; hist_s[i] = 0; }
    __syncthreads();
    int cu_[CEDGE], ct_[CEDGE], ot_[CEDGE], os_[CEDGE];
    #pragma unroll
    for (int j = 0; j < CEDGE; ++j) {
        const int idx = t + j * 512;
        if (idx < PCHUNK) {
            const int e = ebase + idx;
            const int src = ei[e], trg = ei[E_L + e];
            cu_[j] = src; ct_[j] = trg;
            ot_[j] = atomicAdd(&hist_t[trg >> BSH], 1);
            os_[j] = atomicAdd(&hist_s[src >> BSH], 1);
        } else { cu_[j] = 0; ct_[j] = -1; ot_[j] = 0; os_[j] = 0; }
    }
    __syncthreads();
    for (int i = t; i < NB; i += 512) {
        res_t[i] = hist_t[i] ? atomicAdd(&cur_t[i], hist_t[i]) : 0;
        res_s[i] = hist_s[i] ? atomicAdd(&cur_s[i], hist_s[i]) : 0;
    }
    __syncthreads();
    #pragma unroll
    for (int j = 0; j < CEDGE; ++j) {
        if (ct_[j] >= 0) {
            const int src = cu_[j], trg = ct_[j];
            const int st = res_t[trg >> BSH] + ot_[j];
            const int ss = res_s[src >> BSH] + os_[j];
            if (st < CAP)
                trgbuf[(trg >> BSH) * CAP + st] =
                    (((l << 6) | (trg & 63)) << 17) | (src + l * N_NODES);
            if (ss < CAP)
                srcbuf[(src >> BSH) * CAP + ss] =
                    (unsigned char)((l << 6) | (src & 63));
        }
    }
}

// ---------------------------------------------------------------------------
// K2: proj fused with degree counting. One block per bucket (64 nodes):
// histogram trgbuf -> ht (outdeg, used in-block) and srcbuf -> hs (written
// to global cnt_src for mega). Then 8 sub-tiles of the proven 8-node proj
// pattern: scaled[(l*N+n)*32+f] = (x @ Wp^T) * rsqrt(ht+2).
// ---------------------------------------------------------------------------
__global__ __launch_bounds__(256) void proj_kernel(
    const float* __restrict__ x, const float* __restrict__ Wp,
    const int* __restrict__ cur_t, const int* __restrict__ cur_s,
    const int* __restrict__ trgbuf, const unsigned char* __restrict__ srcbuf,
    int* __restrict__ cnt_src, float* __restrict__ scaled) {
    __shared__ float Wtt[64][132];   // Wtt[o][k] = Wp[o*128+k]
    __shared__ float xt[8][F_IN];
    __shared__ int ht[128], hs[128];
    const int t = threadIdx.x, b = blockIdx.x;
    for (int i = t; i < 64 * F_IN; i += 256)
        Wtt[i >> 7][i & 127] = Wp[i];
    if (t < 128) { ht[t] = 0; hs[t] = 0; }
    __syncthreads();
    const int ct = min(cur_t[b], CAP), cs = min(cur_s[b], CAP);
    for (int i = t; i < ct; i += 256)
        atomicAdd(&ht[(trgbuf[b * CAP + i] >> 17) & 127], 1);
    for (int i = t; i < cs; i += 256)
        atomicAdd(&hs[srcbuf[b * CAP + i] & 127], 1);
    __syncthreads();
    const int base = b * BNODES;
    if (t < 128) {
        const int n = base + (t & 63);
        if (n < N_NODES) cnt_src[(t >> 6) * N_NODES + n] = hs[t];
    }
    const int lane = t & 63, w = t >> 6;
    const int l = lane >> 5, f = lane & 31;
    for (int s = 0; s < 8; ++s) {
        const int nb0 = base + s * 8;         // first node of sub-tile
        if (nb0 >= N_NODES) break;            // uniform: tail bucket
        __syncthreads();                      // xt reuse guard
        {   // stage 8 nodes x 128 floats (guard OOB nodes of last bucket)
            float4 val = make_float4(0.f, 0.f, 0.f, 0.f);
            if (nb0 + (t >> 5) < N_NODES)
                val = ((const float4*)(x + (size_t)nb0 * F_IN))[t];
            ((float4*)&xt[0][0])[t] = val;
        }
        __syncthreads();
        const int i0 = s * 8 + w, i1 = s * 8 + w + 4;  // node-in-bucket
        float acc0 = 0.f, acc1 = 0.f;
        #pragma unroll
        for (int k = 0; k < F_IN; k += 4) {
            float4 wv = *(const float4*)&Wtt[lane][k];
            float4 x0 = *(const float4*)&xt[w][k];
            float4 x1 = *(const float4*)&xt[w + 4][k];
            acc0 += wv.x * x0.x + wv.y * x0.y + wv.z * x0.z + wv.w * x0.w;
            acc1 += wv.x * x1.x + wv.y * x1.y + wv.z * x1.z + wv.w * x1.w;
        }
        const int n0 = base + i0, n1 = base + i1;
        if (n0 < N_NODES) {
            const float od = rsqrtf((float)(ht[(l << 6) | i0] + 2));
            scaled[(size_t)(l * N_NODES + n0) * F_OUT + f] = acc0 * od;
        }
        if (n1 < N_NODES) {
            const float od = rsqrtf((float)(ht[(l << 6) | i1] + 2));
            scaled[(size_t)(l * N_NODES + n1) * F_OUT + f] = acc1 * od;
        }
    }
}

// ---------------------------------------------------------------------------
// K3: mega on HALF-buckets (32 nodes, 2 blocks per bucket, 256 threads,
// ~22.8KB LDS -> 7 blocks/CU, 1564 blocks -> 6.1/CU: 2x occupancy vs r10).
// Scans parent bucket's trgbuf filtering by half bit (trg&32 = rr bit 5);
// rdeg from own histogram (cnt_trg global array no longer needed).
// Dual-row gather (both layers of one node per 8-lane group) -> fold ->
// 64->32 merge GEMM.
// ---------------------------------------------------------------------------
__global__ __launch_bounds__(256) void mega_kernel(
    const int* __restrict__ cur_t, const int* __restrict__ trgbuf,
    const int* __restrict__ cnt_src, const float* __restrict__ scaled,
    const float* __restrict__ Wm, const float* __restrict__ bias,
    float* __restrict__ out) {
    __shared__ int   colx[HCAP];       // 5 KB sorted sources (this half)
    __shared__ int   rdeg[64], rp[64], cursor[64], sc[64];
    __shared__ float h[32][64];        // 8 KB
    __shared__ float Wt[64][32];       // 8 KB, Wt[k][o] = Wm[o*64+k]
    __shared__ float bs[64];
    const int t = threadIdx.x, b2 = blockIdx.x;
    const int b = b2 >> 1, half = b2 & 1;
    for (int i = t; i < 2048; i += 256)
        Wt[i >> 5][i & 31] = Wm[(i & 31) * 64 + (i >> 5)];
    if (t < 64) { bs[t] = bias[t]; rdeg[t] = 0; }
    __syncthreads();
    const int total = min(cur_t[b], CAP);
    const int tb = b * CAP;
    // pass 1: histogram this half's rows (row = l*32 + (trg&31))
    for (int i = t; i < total; i += 256) {
        const int rr = (trgbuf[tb + i] >> 17) & 127;
        if (((rr >> 5) & 1) == half)
            atomicAdd(&rdeg[((rr >> 6) << 5) | (rr & 31)], 1);
    }
    __syncthreads();
    int cnt_r = 0;
    if (t < 64) { cnt_r = rdeg[t]; sc[t] = cnt_r; }
    __syncthreads();
    for (int off = 1; off < 64; off <<= 1) {
        int add = (t < 64 && t >= off) ? sc[t - off] : 0;
        __syncthreads();
        if (t < 64) sc[t] += add;
        __syncthreads();
    }
    if (t < 64) { rp[t] = sc[t] - cnt_r; cursor[t] = sc[t] - cnt_r; }
    __syncthreads();
    // pass 2: counting-sort scatter into colx (LDS only)
    for (int i = t; i < total; i += 256) {
        const int p = trgbuf[tb + i];
        const int rr = (p >> 17) & 127;
        if (((rr >> 5) & 1) == half) {
            const int slot = atomicAdd(&cursor[((rr >> 6) << 5) | (rr & 31)], 1);
            if (slot < HCAP) colx[slot] = p & 0x1FFFF;
        }
    }
    __syncthreads();
    // dual-row gather: group = node nl, rows nl (l=0) and nl+32 (l=1)
    const int nl = t >> 3, f = (t & 7) * 4;
    const int n = b * BNODES + half * 32 + nl;
    if (n < N_NODES) {
        const int s0 = rp[nl],      d0 = rdeg[nl];
        const int s1 = rp[nl + 32], d1 = rdeg[nl + 32];
        float4 acc0 = make_float4(0.f, 0.f, 0.f, 0.f);
        float4 acc1 = make_float4(0.f, 0.f, 0.f, 0.f);
        const int m = (d0 > d1) ? d0 : d1;
        #pragma unroll 4
        for (int i = 0; i < m; ++i) {
            if (i < d0) {
                const int u = colx[s0 + i];
                const float4 g = *(const float4*)(scaled + (size_t)u * F_OUT + f);
                acc0.x += g.x; acc0.y += g.y; acc0.z += g.z; acc0.w += g.w;
            }
            if (i < d1) {
                const int u = colx[s1 + i];
                const float4 g = *(const float4*)(scaled + (size_t)u * F_OUT + f);
                acc1.x += g.x; acc1.y += g.y; acc1.z += g.z; acc1.w += g.w;
            }
        }
        // self(l0)=scaled[v]; inter(l0)=scaled[vp]; layer1 shares the pair
        const int v = n, vp = N_NODES + n;
        const float4 sv = *(const float4*)(scaled + (size_t)v  * F_OUT + f);
        const float4 pv = *(const float4*)(scaled + (size_t)vp * F_OUT + f);
        const float id0 = rsqrtf((float)(cnt_src[v]  + 2));
        const float id1 = rsqrtf((float)(cnt_src[vp] + 2));
        float4 h0, h1;
        h0.x = (acc0.x + sv.x + pv.x) * id0 + bs[f + 0];
        h0.y = (acc0.y + sv.y + pv.y) * id0 + bs[f + 1];
        h0.z = (acc0.z + sv.z + pv.z) * id0 + bs[f + 2];
        h0.w = (acc0.w + sv.w + pv.w) * id0 + bs[f + 3];
        h1.x = (acc1.x + sv.x + pv.x) * id1 + bs[32 + f + 0];
        h1.y = (acc1.y + sv.y + pv.y) * id1 + bs[32 + f + 1];
        h1.z = (acc1.z + sv.z + pv.z) * id1 + bs[32 + f + 2];
        h1.w = (acc1.w + sv.w + pv.w) * id1 + bs[32 + f + 3];
        h0.x = (h0.x >= 0.f) ? h0.x : NEG_SLOPE * h0.x;
        h0.y = (h0.y >= 0.f) ? h0.y : NEG_SLOPE * h0.y;
        h0.z = (h0.z >= 0.f) ? h0.z : NEG_SLOPE * h0.z;
        h0.w = (h0.w >= 0.f) ? h0.w : NEG_SLOPE * h0.w;
        h1.x = (h1.x >= 0.f) ? h1.x : NEG_SLOPE * h1.x;
        h1.y = (h1.y >= 0.f) ? h1.y : NEG_SLOPE * h1.y;
        h1.z = (h1.z >= 0.f) ? h1.z : NEG_SLOPE * h1.z;
        h1.w = (h1.w >= 0.f) ? h1.w : NEG_SLOPE * h1.w;
        *(float4*)&h[nl][f]      = h0;
        *(float4*)&h[nl][32 + f] = h1;
    }
    __syncthreads();
    // merge GEMM: out[n][o] = sum_k h[n][k] * Wm[o][k]
    for (int i = t; i < 32 * 32; i += 256) {
        const int nl2 = i >> 5, o = i & 31;
        const int n2 = b * BNODES + half * 32 + nl2;
        if (n2 < N_NODES) {
            float acc = 0.f;
            #pragma unroll
            for (int k = 0; k < 64; ++k)
                acc += h[nl2][k] * Wt[k][o];   // h: broadcast; Wt: cf
            out[(size_t)n2 * F_OUT + o] = acc;
        }
    }
}

// ---------------------------------------------------------------------------
extern "C" void kernel_launch(void* const* d_in, const int* in_sizes, int n_in,
                              void* d_out, int out_size, void* d_ws, size_t ws_size,
                              hipStream_t stream) {
    const float* x    = (const float*)d_in[0];
    const int*   e0   = (const int*)d_in[1];
    const int*   e1   = (const int*)d_in[2];
    const float* Wp   = (const float*)d_in[3];
    const float* Wm   = (const float*)d_in[4];
    const float* bias = (const float*)d_in[5];
    float* out = (float*)d_out;

    // workspace (~22.5 MB). srcbuf NO LONGER aliases scaled: proj reads
    // srcbuf while concurrently writing scaled (fused count) — must be
    // disjoint. Known-safe ws >= 26.4 MB (round 1).
    float* scaled = (float*)d_ws;                          // 12.8 MB
    int* trgbuf  = (int*)(scaled + (size_t)LN * F_OUT);    // 7.40 MB
    unsigned char* srcbuf = (unsigned char*)(trgbuf + (size_t)NB * CAP); // 1.85 MB
    int* cur_t   = (int*)(srcbuf + (size_t)NB * CAP);      // NB ints
    int* cur_s   = cur_t + NB;                             // NB ints
    int* cnt_src = cur_s + NB;                             // 400 KB

    hipMemsetAsync(cur_t, 0, 2 * NB * sizeof(int), stream);

    partition_kernel<<<PBLOCKS, 512, 0, stream>>>(e0, e1, cur_t, cur_s,
                                                  trgbuf, srcbuf);
    proj_kernel<<<NB, 256, 0, stream>>>(x, Wp, cur_t, cur_s, trgbuf, srcbuf,
                                        cnt_src, scaled);
    mega_kernel<<<2 * NB, 256, 0, stream>>>(cur_t, trgbuf, cnt_src,
                                            scaled, Wm, bias, out);
}

// Round 12
// 194.605 us; speedup vs baseline: 1.2664x; 1.2664x over previous
//
#include <hip/hip_runtime.h>

#define N_NODES 50000
#define F_IN 128
#define F_OUT 32
#define E_L 800000
#define NEG_SLOPE 0.2f
#define LN 100000                 // 2 * N_NODES
#define BSH 6                     // 64 nodes per bucket
#define BNODES 64
#define NB 782                    // ceil(50000/64)
#define CAP 2368                  // bucket cap: mean 2048 + ~7 sigma
#define HCAP 1280                 // half-bucket cap
#define PBLOCKS 256
#define PCHUNK 6250               // PBLOCKS * PCHUNK == NE; 128*6250 == E_L
#define CEDGE 13                  // ceil(PCHUNK / 512)
#define PGRID 782                 // proj: ceil(N/64)

// ---------------------------------------------------------------------------
// K1: bucket partition (r10 measured-best, unchanged). trg entry (rr:7|u:17),
// rr=(l<<6)|(trg&63), u=src+l*N; src side 1 byte (l<<6)|(src&63). LDS hist
// reserves contiguous global ranges; phase A caches atomic returns -> phase C
// atomic-free. NO global atomics (r8: 3.2M atomics = ~102MB fabric RMW).
// ---------------------------------------------------------------------------
__global__ __launch_bounds__(512) void partition_kernel(
    const int* __restrict__ e0, const int* __restrict__ e1,
    int* __restrict__ cur_t, int* __restrict__ cur_s,
    int* __restrict__ trgbuf, unsigned char* __restrict__ srcbuf) {
    __shared__ int hist_t[NB], hist_s[NB], res_t[NB], res_s[NB];
    const int t = threadIdx.x, b = blockIdx.x;
    const int l = (b >= PBLOCKS / 2) ? 1 : 0;
    const int* __restrict__ ei = l ? e1 : e0;
    const int ebase = b * PCHUNK - l * E_L;
    for (int i = t; i < NB; i += 512) { hist_t[i] = 0; hist_s[i] = 0; }
    __syncthreads();
    int cu_[CEDGE], ct_[CEDGE], ot_[CEDGE], os_[CEDGE];
    #pragma unroll
    for (int j = 0; j < CEDGE; ++j) {
        const int idx = t + j * 512;
        if (idx < PCHUNK) {
            const int e = ebase + idx;
            const int src = ei[e], trg = ei[E_L + e];
            cu_[j] = src; ct_[j] = trg;
            ot_[j] = atomicAdd(&hist_t[trg >> BSH], 1);
            os_[j] = atomicAdd(&hist_s[src >> BSH], 1);
        } else { cu_[j] = 0; ct_[j] = -1; ot_[j] = 0; os_[j] = 0; }
    }
    __syncthreads();
    for (int i = t; i < NB; i += 512) {
        res_t[i] = hist_t[i] ? atomicAdd(&cur_t[i], hist_t[i]) : 0;
        res_s[i] = hist_s[i] ? atomicAdd(&cur_s[i], hist_s[i]) : 0;
    }
    __syncthreads();
    #pragma unroll
    for (int j = 0; j < CEDGE; ++j) {
        if (ct_[j] >= 0) {
            const int src = cu_[j], trg = ct_[j];
            const int st = res_t[trg >> BSH] + ot_[j];
            const int ss = res_s[src >> BSH] + os_[j];
            if (st < CAP)
                trgbuf[(trg >> BSH) * CAP + st] =
                    (((l << 6) | (trg & 63)) << 17) | (src + l * N_NODES);
            if (ss < CAP)
                srcbuf[(src >> BSH) * CAP + ss] =
                    (unsigned char)((l << 6) | (src & 63));
        }
    }
}

// ---------------------------------------------------------------------------
// K2: per-bucket LDS hists -> dense cnt_trg / cnt_src. (r10 unchanged)
// ---------------------------------------------------------------------------
__global__ __launch_bounds__(256) void count_kernel(
    const int* __restrict__ cur_t, const int* __restrict__ cur_s,
    const int* __restrict__ trgbuf, const unsigned char* __restrict__ srcbuf,
    int* __restrict__ cnt_trg, int* __restrict__ cnt_src) {
    __shared__ int ht[128], hs[128];
    const int t = threadIdx.x, b = blockIdx.x;
    if (t < 128) { ht[t] = 0; hs[t] = 0; }
    __syncthreads();
    const int ct = min(cur_t[b], CAP), cs = min(cur_s[b], CAP);
    for (int i = t; i < ct; i += 256)
        atomicAdd(&ht[(trgbuf[b * CAP + i] >> 17) & 127], 1);
    for (int i = t; i < cs; i += 256)
        atomicAdd(&hs[srcbuf[b * CAP + i] & 127], 1);
    __syncthreads();
    if (t < 128) {
        const int l = t >> 6, n = b * BNODES + (t & 63);
        if (n < N_NODES) {
            cnt_trg[l * N_NODES + n] = ht[t];
            cnt_src[l * N_NODES + n] = hs[t];
        }
    }
}

// ---------------------------------------------------------------------------
// K3: proj, register-tiled. Block = 64 nodes x 64 outs; thread = 4n x 4o.
// Per k: ONE float4 of transposed-x + ONE float4 of transposed-W = 32B LDS
// for 16 FMAs (2B/FMA; old kernel was 6B/FMA -> LDS-throughput bound 95us).
// k staged in 4 chunks of 32 (xts/wts [32][66], stride 66 -> <=2-way banks).
// ---------------------------------------------------------------------------
__global__ __launch_bounds__(256) void proj_kernel(
    const float* __restrict__ x, const float* __restrict__ Wp,
    const int* __restrict__ cnt_trg, float* __restrict__ scaled) {
    __shared__ float xts[32][66];    // [k][node]   8.25 KB
    __shared__ float wts[32][66];    // [k][out]    8.25 KB (64 used)
    const int t = threadIdx.x;
    const int tx = t & 15, ty = t >> 4;       // tx: node grp, ty: out grp
    const int n0 = tx * 4, o0 = ty * 4;
    const int l = ty >> 3, f0 = o0 & 31;      // out grp within one layer
    const int base = blockIdx.x * BNODES;
    const int sn = t >> 3, sk = (t & 7) * 4;  // staging coords
    float acc[4][4];
    #pragma unroll
    for (int i = 0; i < 4; ++i)
        #pragma unroll
        for (int j = 0; j < 4; ++j) acc[i][j] = 0.f;
    for (int kc = 0; kc < 4; ++kc) {
        const int k0 = kc * 32;
        __syncthreads();                      // reuse guard
        #pragma unroll
        for (int p = 0; p < 2; ++p) {         // stage x transposed
            const int n = sn + p * 32;
            const int gn = base + n;
            float4 v = make_float4(0.f, 0.f, 0.f, 0.f);
            if (gn < N_NODES)
                v = *(const float4*)(x + (size_t)gn * F_IN + k0 + sk);
            xts[sk + 0][n] = v.x; xts[sk + 1][n] = v.y;
            xts[sk + 2][n] = v.z; xts[sk + 3][n] = v.w;
        }
        #pragma unroll
        for (int p = 0; p < 2; ++p) {         // stage W transposed
            const int o = sn + p * 32;
            const float4 v = *(const float4*)(Wp + (size_t)o * F_IN + k0 + sk);
            wts[sk + 0][o] = v.x; wts[sk + 1][o] = v.y;
            wts[sk + 2][o] = v.z; wts[sk + 3][o] = v.w;
        }
        __syncthreads();
        #pragma unroll
        for (int k = 0; k < 32; ++k) {
            const float4 xv = *(const float4*)&xts[k][n0];  // bcast x4 + 2-way
            const float4 wv = *(const float4*)&wts[k][o0];  // bcast x16
            acc[0][0] += xv.x * wv.x; acc[0][1] += xv.x * wv.y;
            acc[0][2] += xv.x * wv.z; acc[0][3] += xv.x * wv.w;
            acc[1][0] += xv.y * wv.x; acc[1][1] += xv.y * wv.y;
            acc[1][2] += xv.y * wv.z; acc[1][3] += xv.y * wv.w;
            acc[2][0] += xv.z * wv.x; acc[2][1] += xv.z * wv.y;
            acc[2][2] += xv.z * wv.z; acc[2][3] += xv.z * wv.w;
            acc[3][0] += xv.w * wv.x; acc[3][1] += xv.w * wv.y;
            acc[3][2] += xv.w * wv.z; acc[3][3] += xv.w * wv.w;
        }
    }
    // epilogue: v = l*N + gn; scaled[v*32 + f0..f0+3] = acc[i][*] * rsqrt(deg)
    #pragma unroll
    for (int i = 0; i < 4; ++i) {
        const int gn = base + n0 + i;
        if (gn < N_NODES) {
            const int v = l * N_NODES + gn;
            const float od = rsqrtf((float)(cnt_trg[v] + 2));
            float4 r;
            r.x = acc[i][0] * od; r.y = acc[i][1] * od;
            r.z = acc[i][2] * od; r.w = acc[i][3] * od;
            *(float4*)(scaled + (size_t)v * F_OUT + f0) = r;
        }
    }
}

// ---------------------------------------------------------------------------
// K4: mega on HALF-buckets (r11, passed): 2 blocks/bucket x 256 thr, ~22KB
// LDS -> ~2x occupancy vs r10. Histogram own rdeg, LDS counting-sort,
// dual-row gather (both layers of one node per 8-lane group), fold, GEMM.
// ---------------------------------------------------------------------------
__global__ __launch_bounds__(256) void mega_kernel(
    const int* __restrict__ cur_t, const int* __restrict__ trgbuf,
    const int* __restrict__ cnt_src, const float* __restrict__ scaled,
    const float* __restrict__ Wm, const float* __restrict__ bias,
    float* __restrict__ out) {
    __shared__ int   colx[HCAP];
    __shared__ int   rdeg[64], rp[64], cursor[64], sc[64];
    __shared__ float h[32][64];
    __shared__ float Wt[64][32];
    __shared__ float bs[64];
    const int t = threadIdx.x, b2 = blockIdx.x;
    const int b = b2 >> 1, half = b2 & 1;
    for (int i = t; i < 2048; i += 256)
        Wt[i >> 5][i & 31] = Wm[(i & 31) * 64 + (i >> 5)];
    if (t < 64) { bs[t] = bias[t]; rdeg[t] = 0; }
    __syncthreads();
    const int total = min(cur_t[b], CAP);
    const int tb = b * CAP;
    for (int i = t; i < total; i += 256) {
        const int rr = (trgbuf[tb + i] >> 17) & 127;
        if (((rr >> 5) & 1) == half)
            atomicAdd(&rdeg[((rr >> 6) << 5) | (rr & 31)], 1);
    }
    __syncthreads();
    int cnt_r = 0;
    if (t < 64) { cnt_r = rdeg[t]; sc[t] = cnt_r; }
    __syncthreads();
    for (int off = 1; off < 64; off <<= 1) {
        int add = (t < 64 && t >= off) ? sc[t - off] : 0;
        __syncthreads();
        if (t < 64) sc[t] += add;
        __syncthreads();
    }
    if (t < 64) { rp[t] = sc[t] - cnt_r; cursor[t] = sc[t] - cnt_r; }
    __syncthreads();
    for (int i = t; i < total; i += 256) {
        const int p = trgbuf[tb + i];
        const int rr = (p >> 17) & 127;
        if (((rr >> 5) & 1) == half) {
            const int slot = atomicAdd(&cursor[((rr >> 6) << 5) | (rr & 31)], 1);
            if (slot < HCAP) colx[slot] = p & 0x1FFFF;
        }
    }
    __syncthreads();
    const int nl = t >> 3, f = (t & 7) * 4;
    const int n = b * BNODES + half * 32 + nl;
    if (n < N_NODES) {
        const int s0 = rp[nl],      d0 = rdeg[nl];
        const int s1 = rp[nl + 32], d1 = rdeg[nl + 32];
        float4 acc0 = make_float4(0.f, 0.f, 0.f, 0.f);
        float4 acc1 = make_float4(0.f, 0.f, 0.f, 0.f);
        const int m = (d0 > d1) ? d0 : d1;
        #pragma unroll 4
        for (int i = 0; i < m; ++i) {
            if (i < d0) {
                const int u = colx[s0 + i];
                const float4 g = *(const float4*)(scaled + (size_t)u * F_OUT + f);
                acc0.x += g.x; acc0.y += g.y; acc0.z += g.z; acc0.w += g.w;
            }
            if (i < d1) {
                const int u = colx[s1 + i];
                const float4 g = *(const float4*)(scaled + (size_t)u * F_OUT + f);
                acc1.x += g.x; acc1.y += g.y; acc1.z += g.z; acc1.w += g.w;
            }
        }
        const int v = n, vp = N_NODES + n;
        const float4 sv = *(const float4*)(scaled + (size_t)v  * F_OUT + f);
        const float4 pv = *(const float4*)(scaled + (size_t)vp * F_OUT + f);
        const float id0 = rsqrtf((float)(cnt_src[v]  + 2));
        const float id1 = rsqrtf((float)(cnt_src[vp] + 2));
        float4 h0, h1;
        h0.x = (acc0.x + sv.x + pv.x) * id0 + bs[f + 0];
        h0.y = (acc0.y + sv.y + pv.y) * id0 + bs[f + 1];
        h0.z = (acc0.z + sv.z + pv.z) * id0 + bs[f + 2];
        h0.w = (acc0.w + sv.w + pv.w) * id0 + bs[f + 3];
        h1.x = (acc1.x + sv.x + pv.x) * id1 + bs[32 + f + 0];
        h1.y = (acc1.y + sv.y + pv.y) * id1 + bs[32 + f + 1];
        h1.z = (acc1.z + sv.z + pv.z) * id1 + bs[32 + f + 2];
        h1.w = (acc1.w + sv.w + pv.w) * id1 + bs[32 + f + 3];
        h0.x = (h0.x >= 0.f) ? h0.x : NEG_SLOPE * h0.x;
        h0.y = (h0.y >= 0.f) ? h0.y : NEG_SLOPE * h0.y;
        h0.z = (h0.z >= 0.f) ? h0.z : NEG_SLOPE * h0.z;
        h0.w = (h0.w >= 0.f) ? h0.w : NEG_SLOPE * h0.w;
        h1.x = (h1.x >= 0.f) ? h1.x : NEG_SLOPE * h1.x;
        h1.y = (h1.y >= 0.f) ? h1.y : NEG_SLOPE * h1.y;
        h1.z = (h1.z >= 0.f) ? h1.z : NEG_SLOPE * h1.z;
        h1.w = (h1.w >= 0.f) ? h1.w : NEG_SLOPE * h1.w;
        *(float4*)&h[nl][f]      = h0;
        *(float4*)&h[nl][32 + f] = h1;
    }
    __syncthreads();
    for (int i = t; i < 32 * 32; i += 256) {
        const int nl2 = i >> 5, o = i & 31;
        const int n2 = b * BNODES + half * 32 + nl2;
        if (n2 < N_NODES) {
            float acc = 0.f;
            #pragma unroll
            for (int k = 0; k < 64; ++k)
                acc += h[nl2][k] * Wt[k][o];
            out[(size_t)n2 * F_OUT + o] = acc;
        }
    }
}

// ---------------------------------------------------------------------------
extern "C" void kernel_launch(void* const* d_in, const int* in_sizes, int n_in,
                              void* d_out, int out_size, void* d_ws, size_t ws_size,
                              hipStream_t stream) {
    const float* x    = (const float*)d_in[0];
    const int*   e0   = (const int*)d_in[1];
    const int*   e1   = (const int*)d_in[2];
    const float* Wp   = (const float*)d_in[3];
    const float* Wm   = (const float*)d_in[4];
    const float* bias = (const float*)d_in[5];
    float* out = (float*)d_out;

    // workspace (~21.0 MB, r10 layout). srcbuf aliases scaled: written by
    // partition, read by count, dead before proj writes scaled.
    float* scaled = (float*)d_ws;                         // 12.8 MB
    unsigned char* srcbuf = (unsigned char*)d_ws;         // 1.85 MB alias
    int* trgbuf  = (int*)((char*)d_ws + (size_t)LN * F_OUT * sizeof(float)); // 7.4 MB
    int* cur_t   = trgbuf + (size_t)NB * CAP;             // NB ints
    int* cur_s   = cur_t + NB;                            // NB ints
    int* cnt_trg = cur_s + NB;                            // 400 KB
    int* cnt_src = cnt_trg + LN;                          // 400 KB

    hipMemsetAsync(cur_t, 0, 2 * NB * sizeof(int), stream);

    partition_kernel<<<PBLOCKS, 512, 0, stream>>>(e0, e1, cur_t, cur_s,
                                                  trgbuf, srcbuf);
    count_kernel<<<NB, 256, 0, stream>>>(cur_t, cur_s, trgbuf, srcbuf,
                                         cnt_trg, cnt_src);
    proj_kernel<<<PGRID, 256, 0, stream>>>(x, Wp, cnt_trg, scaled);
    mega_kernel<<<2 * NB, 256, 0, stream>>>(cur_t, trgbuf, cnt_src,
                                            scaled, Wm, bias, out);
}